// Round 8
// baseline (370.203 us; speedup 1.0000x reference)
//
#include <hip/hip_runtime.h>
#include <hip/hip_bf16.h>
#include <math.h>

#define B_ 2
#define T_ 2048
#define C_ 2048
#define H_ 16
#define KVH_ 4
#define HD_ 128
#define G_ (H_ / KVH_)
#define MROWS (B_ * T_)                    // 4096
#define NQKV (H_ * HD_ + 2 * KVH_ * HD_)   // 3072
#define KOFF (H_ * HD_)                    // 2048
#define VOFF (H_ * HD_ + KVH_ * HD_)       // 2560

typedef __hip_bfloat16 bf16;
typedef short bf16x8 __attribute__((ext_vector_type(8)));   // 8 bf16 = 4 VGPR
typedef short bf16x4 __attribute__((ext_vector_type(4)));   // 4 bf16 = 2 VGPR
typedef float f32x4 __attribute__((ext_vector_type(4)));

__device__ __forceinline__ void gload_lds16(const void* g, void* l) {
  __builtin_amdgcn_global_load_lds(
      (const __attribute__((address_space(1))) unsigned int*)g,
      (__attribute__((address_space(3))) unsigned int*)l, 16, 0, 0);
}

static __device__ __forceinline__ f32x4 mfma16(bf16x4 a, bf16x4 b, f32x4 c) {
#if __has_builtin(__builtin_amdgcn_mfma_f32_16x16x16_bf16)
  return __builtin_amdgcn_mfma_f32_16x16x16_bf16(a, b, c, 0, 0, 0);
#else
  return __builtin_amdgcn_mfma_f32_16x16x16bf16_1k(a, b, c, 0, 0, 0);
#endif
}

// fast RNE f32->bf16 (no NaN handling; inputs are finite probabilities/sums)
static __device__ __forceinline__ short f2bf(float x) {
  unsigned u = __builtin_bit_cast(unsigned, x);
  u += 0x7FFFu + ((u >> 16) & 1u);
  return (short)(u >> 16);
}

static __device__ __forceinline__ float fexp2(float x) {
#if __has_builtin(__builtin_amdgcn_exp2f)
  return __builtin_amdgcn_exp2f(x);
#else
  return exp2f(x);
#endif
}

// ---------------------------------------------------------------------------
// fp32 -> bf16 elementwise cast
// ---------------------------------------------------------------------------
__global__ void cast_bf16_kernel(const float* __restrict__ in, bf16* __restrict__ out, int n) {
  int i = (blockIdx.x * 256 + threadIdx.x) * 4;
  if (i >= n) return;
  float4 v = *(const float4*)(in + i);
  out[i + 0] = __float2bfloat16(v.x);
  out[i + 1] = __float2bfloat16(v.y);
  out[i + 2] = __float2bfloat16(v.z);
  out[i + 3] = __float2bfloat16(v.w);
}

// ---------------------------------------------------------------------------
// fp32 [R][Ccols] -> bf16 out[Ccols][R]  (for wo)
// ---------------------------------------------------------------------------
__global__ __launch_bounds__(256) void transpose_cast(const float* __restrict__ in,
                                                      bf16* __restrict__ out,
                                                      int R, int Ccols) {
  __shared__ float t[32][33];
  const int tx = threadIdx.x & 31, ty = threadIdx.x >> 5;
  const int r0 = blockIdx.y * 32, c0 = blockIdx.x * 32;
#pragma unroll
  for (int it = 0; it < 4; ++it)
    t[ty + 8 * it][tx] = in[(size_t)(r0 + ty + 8 * it) * Ccols + c0 + tx];
  __syncthreads();
#pragma unroll
  for (int it = 0; it < 4; ++it)
    out[(size_t)(c0 + ty + 8 * it) * R + r0 + tx] = __float2bfloat16(t[tx][ty + 8 * it]);
}

// ---------------------------------------------------------------------------
// Fused wq|wk|wv [2048][*] -> wqkvT [3072][2048] transpose-cast (1 launch)
// ---------------------------------------------------------------------------
__global__ __launch_bounds__(256) void transpose_cast_qkvw(
    const float* __restrict__ wq, const float* __restrict__ wk,
    const float* __restrict__ wv, bf16* __restrict__ outT) {
  __shared__ float t[32][33];
  const int tx = threadIdx.x & 31, ty = threadIdx.x >> 5;
  const int r0 = blockIdx.y * 32;           // k-dim
  const int c0 = blockIdx.x * 32;           // fused n-dim 0..3071
  const float* src;
  int nn, ld;
  if (c0 < KOFF)      { src = wq; nn = c0;        ld = 2048; }
  else if (c0 < VOFF) { src = wk; nn = c0 - KOFF; ld = 512; }
  else                { src = wv; nn = c0 - VOFF; ld = 512; }
#pragma unroll
  for (int it = 0; it < 4; ++it)
    t[ty + 8 * it][tx] = src[(size_t)(r0 + ty + 8 * it) * ld + nn + tx];
  __syncthreads();
#pragma unroll
  for (int it = 0; it < 4; ++it)
    outT[(size_t)(c0 + ty + 8 * it) * 2048 + r0 + tx] = __float2bfloat16(t[tx][ty + 8 * it]);
}

// ---------------------------------------------------------------------------
// RoPE in place on q+k head-rows of qkv (cols 0..2559 = 20 contiguous heads).
// ---------------------------------------------------------------------------
__global__ void rope_bf16(bf16* __restrict__ buf) {
  const int row = blockIdx.x / 20;         // b*T + t
  const int hh = blockIdx.x % 20;          // 0..15 q heads, 16..19 k heads
  const int t = row % T_;
  const int d = threadIdx.x;
  bf16* rp = buf + (size_t)row * NQKV + hh * HD_;
  float vd = __bfloat162float(rp[d]);
  float vp = __bfloat162float(rp[d ^ 64]);
  __syncthreads();
  const int i = d & 63;
  float invf = fexp2(-(float)i * (13.287712379549449f / 64.0f));
  float ang = (float)t * invf;
  float s, c;
  __sincosf(ang, &s, &c);
  rp[d] = __float2bfloat16((d < 64) ? (vd * c - vp * s) : (vd * c + vp * s));
}

// ---------------------------------------------------------------------------
// Pack RoPE'd K into MFMA-fragment-major order:
// kp chunk ((bk*64 + tile)*8 + kt*4 + c)*512 + L*8 holds
//   K[b, t = tile*32 + 16*kt + (L&15), kvh][c*32 + (L>>4)*8 .. +8]
// so flash's kf loads are lane-contiguous dwordx4 (1KB/instr).
// ---------------------------------------------------------------------------
__global__ __launch_bounds__(256) void pack_k(const bf16* __restrict__ qkv,
                                              bf16* __restrict__ kp) {
  const int tile = blockIdx.x & 63;
  const int bk = blockIdx.x >> 6;          // b*KVH + kvh
  const int b = bk >> 2, kvh = bk & 3;
#pragma unroll
  for (int u = 0; u < 2; ++u) {
    const int t = threadIdx.x + u * 256;   // chunk id 0..511
    const int kc = t >> 6, L = t & 63;
    const bf16* src = qkv +
        (size_t)(b * T_ + tile * 32 + 16 * (kc >> 2) + (L & 15)) * NQKV +
        KOFF + kvh * HD_ + (kc & 3) * 32 + (L >> 4) * 8;
    bf16x8 v = *(const bf16x8*)src;
    *(bf16x8*)(kp + ((size_t)(bk * 64 + tile) * 8 + kc) * 512 + L * 8) = v;
  }
}

// ---------------------------------------------------------------------------
// Pack V into PV A-fragment-major order (replaces transpose_v):
// vp chunk ((bk*64 + tile)*8 + ht)*512 + L*8 holds 8 bf16:
//   j<4 : V[b, t = tile*32 + (L>>4)*4 + j, kvh][ht*16 + (L&15)]      (kt=0)
//   j>=4: V[b, t = tile*32 + 16 + (L>>4)*4 + (j-4), kvh][ht*16+(L&15)] (kt=1)
// ---------------------------------------------------------------------------
__global__ __launch_bounds__(256) void pack_v(const bf16* __restrict__ qkv,
                                              bf16* __restrict__ vp) {
  const int tile = blockIdx.x & 63;
  const int bk = blockIdx.x >> 6;
  const int b = bk >> 2, kvh = bk & 3;
#pragma unroll
  for (int u = 0; u < 2; ++u) {
    const int t = threadIdx.x + u * 256;
    const int ht = t >> 6, L = t & 63;
    const int colL = L & 15, quad = L >> 4;
    const bf16* base = qkv + (size_t)(b * T_ + tile * 32 + quad * 4) * NQKV +
                       VOFF + kvh * HD_ + ht * 16 + colL;
    bf16x8 v;
#pragma unroll
    for (int j = 0; j < 4; ++j) {
      v[j]     = *(const short*)(base + (size_t)j * NQKV);
      v[j + 4] = *(const short*)(base + (size_t)(16 + j) * NQKV);
    }
    *(bf16x8*)(vp + ((size_t)(bk * 64 + tile) * 8 + ht) * 512 + L * 8) = v;
  }
}

// ---------------------------------------------------------------------------
// bf16 MFMA GEMM (m97 structure): C[M,N] = A[M,K] @ Bt[N,K]^T (+ bias)
// ---------------------------------------------------------------------------
template <bool BF16OUT>
__global__ __launch_bounds__(256, 2) void gemm_mfma(
    const bf16* __restrict__ A, const bf16* __restrict__ Bt, void* __restrict__ Cout,
    const float* __restrict__ bq, const float* __restrict__ bk2,
    const float* __restrict__ bv2, int M, int N, int K) {
  __shared__ __align__(16) bf16 As[128 * 32];
  __shared__ __align__(16) bf16 Bs[128 * 32];
  const int tid = threadIdx.x;
  const int w = tid >> 6, lane = tid & 63;
  const int colL = lane & 15, quad = lane >> 4;
  const int wm = w & 1, wn = w >> 1;
  const int r0 = blockIdx.y * 128, c0 = blockIdx.x * 128;

  f32x4 acc[4][4];
  const f32x4 zero = {0.f, 0.f, 0.f, 0.f};
#pragma unroll
  for (int mt = 0; mt < 4; ++mt)
#pragma unroll
    for (int nt = 0; nt < 4; ++nt) acc[mt][nt] = zero;

  for (int k0 = 0; k0 < K; k0 += 32) {
    __syncthreads();
#pragma unroll
    for (int it = 0; it < 2; ++it) {
      const int seg = it * 4 + w;
      const int idx = seg * 64 + lane;
      const int row = idx >> 2, off = idx & 3;
      gload_lds16(A + (size_t)(r0 + row) * K + k0 + off * 8, &As[seg * 512]);
      gload_lds16(Bt + (size_t)(c0 + row) * K + k0 + off * 8, &Bs[seg * 512]);
    }
    __syncthreads();
    bf16x8 af[4], bfv[4];
#pragma unroll
    for (int mt = 0; mt < 4; ++mt)
      af[mt] = *(const bf16x8*)&As[(wm * 64 + mt * 16 + colL) * 32 + quad * 8];
#pragma unroll
    for (int nt = 0; nt < 4; ++nt)
      bfv[nt] = *(const bf16x8*)&Bs[(wn * 64 + nt * 16 + colL) * 32 + quad * 8];
#pragma unroll
    for (int mt = 0; mt < 4; ++mt)
#pragma unroll
      for (int nt = 0; nt < 4; ++nt)
        acc[mt][nt] =
            __builtin_amdgcn_mfma_f32_16x16x32_bf16(af[mt], bfv[nt], acc[mt][nt], 0, 0, 0);
  }

#pragma unroll
  for (int nt = 0; nt < 4; ++nt) {
    const int c = c0 + wn * 64 + nt * 16 + colL;
    float bias = 0.f;
    if (bq) bias = (c < KOFF) ? bq[c] : (c < VOFF ? bk2[c - KOFF] : bv2[c - VOFF]);
#pragma unroll
    for (int mt = 0; mt < 4; ++mt) {
#pragma unroll
      for (int i = 0; i < 4; ++i) {
        const int r = r0 + wm * 64 + mt * 16 + quad * 4 + i;
        const float v = acc[mt][nt][i] + bias;
        if (BF16OUT)
          ((bf16*)Cout)[(size_t)r * N + c] = __float2bfloat16(v);
        else
          ((float*)Cout)[(size_t)r * N + c] = v;
      }
    }
  }
}

// ---------------------------------------------------------------------------
// Causal GQA flash attention v7: LDS-FREE streaming.
// One wave (64-thr block) owns 32 q rows and streams its whole kv range from
// fragment-major packed K'/V' (every load = coalesced 1KB dwordx4 to regs).
// No barriers, no LDS, no staging — waves fully independent; 2 waves/SIMD,
// ~8 waves/CU resident hide each other's L2 latency.
// Transposed math (verified r3): S^T = K*Q^T; O^T = V^T*P^T, P in registers;
// fixed-max softmax (exact by shift-invariance).
// Grid 2048 blocks (heavy q-tiles first for backfill).
// ---------------------------------------------------------------------------
#define FA_SCL2 (0.08838834764831845f * 1.4426950408889634f)  // scale * log2(e)
#define FA_M2 16.0f                                           // fixed max (exp2 domain)

__global__ __launch_bounds__(64) void flash_mfma7(
    const bf16* __restrict__ qkv, const bf16* __restrict__ kp,
    const bf16* __restrict__ vp, bf16* __restrict__ ao) {
  const int id = blockIdx.x;
  const int j = 63 - (id & 63);            // q-tile index, heavy-first
  const int hb = id >> 6;                  // b*16 + h
  const int h = hb & 15, b = hb >> 4;
  const int bk = (b << 2) | (h >> 2);
  const int lane = threadIdx.x & 63;
  const int colL = lane & 15, quad = lane >> 4;
  const int myq0 = j * 32;

  // Q fragments (B-operand of K·Q^T)
  bf16x8 qf[2][4];
  {
    const bf16* qg = qkv + (size_t)(b * T_ + myq0) * NQKV + h * HD_;
#pragma unroll
    for (int mq = 0; mq < 2; ++mq)
#pragma unroll
      for (int c = 0; c < 4; ++c)
        qf[mq][c] = *(const bf16x8*)(qg + (size_t)(mq * 16 + colL) * NQKV + c * 32 + quad * 8);
  }

  f32x4 o[2][8];
  const f32x4 zero = {0.f, 0.f, 0.f, 0.f};
#pragma unroll
  for (int mq = 0; mq < 2; ++mq)
#pragma unroll
    for (int ht = 0; ht < 8; ++ht) o[mq][ht] = zero;
  float l_[2] = {0.f, 0.f};

  const bf16* kpb = kp + (size_t)bk * 64 * 4096 + lane * 8;
  const bf16* vpb = vp + (size_t)bk * 64 * 4096 + lane * 8;

  // ---- full (unmasked) tiles 0..j-1 ----
  for (int tt = 0; tt < j; ++tt) {
    const bf16* kt_ = kpb + (size_t)tt * 4096;
    const bf16* vt_ = vpb + (size_t)tt * 4096;
    bf16x8 kf[8], vf8[8];
#pragma unroll
    for (int kc = 0; kc < 8; ++kc) kf[kc] = *(const bf16x8*)(kt_ + kc * 512);
#pragma unroll
    for (int ht = 0; ht < 8; ++ht) vf8[ht] = *(const bf16x8*)(vt_ + ht * 512);

    f32x4 s_[2][2];
    s_[0][0] = zero; s_[0][1] = zero; s_[1][0] = zero; s_[1][1] = zero;
#pragma unroll
    for (int c = 0; c < 4; ++c)
#pragma unroll
      for (int mq = 0; mq < 2; ++mq) {
        s_[0][mq] = __builtin_amdgcn_mfma_f32_16x16x32_bf16(kf[c],     qf[mq][c], s_[0][mq], 0, 0, 0);
        s_[1][mq] = __builtin_amdgcn_mfma_f32_16x16x32_bf16(kf[4 + c], qf[mq][c], s_[1][mq], 0, 0, 0);
      }

    bf16x4 pf[2][2];
#pragma unroll
    for (int kt = 0; kt < 2; ++kt)
#pragma unroll
      for (int mq = 0; mq < 2; ++mq) {
        float pv[4];
#pragma unroll
        for (int i = 0; i < 4; ++i)
          pv[i] = fexp2(fmaf(s_[kt][mq][i], FA_SCL2, -FA_M2));
        l_[mq] += (pv[0] + pv[1]) + (pv[2] + pv[3]);
        pf[kt][mq] = (bf16x4){f2bf(pv[0]), f2bf(pv[1]), f2bf(pv[2]), f2bf(pv[3])};
      }

#pragma unroll
    for (int ht = 0; ht < 8; ++ht) {
      bf16x4 lo = __builtin_shufflevector(vf8[ht], vf8[ht], 0, 1, 2, 3);
      bf16x4 hi = __builtin_shufflevector(vf8[ht], vf8[ht], 4, 5, 6, 7);
#pragma unroll
      for (int mq = 0; mq < 2; ++mq) {
        o[mq][ht] = mfma16(lo, pf[0][mq], o[mq][ht]);
        o[mq][ht] = mfma16(hi, pf[1][mq], o[mq][ht]);
      }
    }
  }

  // ---- diagonal (masked) tile tt = j ----
  {
    const bf16* kt_ = kpb + (size_t)j * 4096;
    const bf16* vt_ = vpb + (size_t)j * 4096;
    bf16x8 kf[8], vf8[8];
#pragma unroll
    for (int kc = 0; kc < 8; ++kc) kf[kc] = *(const bf16x8*)(kt_ + kc * 512);
#pragma unroll
    for (int ht = 0; ht < 8; ++ht) vf8[ht] = *(const bf16x8*)(vt_ + ht * 512);

    f32x4 s_[2][2];
    s_[0][0] = zero; s_[0][1] = zero; s_[1][0] = zero; s_[1][1] = zero;
#pragma unroll
    for (int c = 0; c < 4; ++c)
#pragma unroll
      for (int mq = 0; mq < 2; ++mq) {
        s_[0][mq] = __builtin_amdgcn_mfma_f32_16x16x32_bf16(kf[c],     qf[mq][c], s_[0][mq], 0, 0, 0);
        s_[1][mq] = __builtin_amdgcn_mfma_f32_16x16x32_bf16(kf[4 + c], qf[mq][c], s_[1][mq], 0, 0, 0);
      }

    bf16x4 pf[2][2];
#pragma unroll
    for (int kt = 0; kt < 2; ++kt)
#pragma unroll
      for (int mq = 0; mq < 2; ++mq) {
        const int qc = mq * 16 + colL;
        const int kb = kt * 16 + quad * 4;
        float pv[4];
#pragma unroll
        for (int i = 0; i < 4; ++i) {
          float e = fexp2(fmaf(s_[kt][mq][i], FA_SCL2, -FA_M2));
          pv[i] = (kb + i <= qc) ? e : 0.f;
        }
        l_[mq] += (pv[0] + pv[1]) + (pv[2] + pv[3]);
        pf[kt][mq] = (bf16x4){f2bf(pv[0]), f2bf(pv[1]), f2bf(pv[2]), f2bf(pv[3])};
      }

#pragma unroll
    for (int ht = 0; ht < 8; ++ht) {
      bf16x4 lo = __builtin_shufflevector(vf8[ht], vf8[ht], 0, 1, 2, 3);
      bf16x4 hi = __builtin_shufflevector(vf8[ht], vf8[ht], 4, 5, 6, 7);
#pragma unroll
      for (int mq = 0; mq < 2; ++mq) {
        o[mq][ht] = mfma16(lo, pf[0][mq], o[mq][ht]);
        o[mq][ht] = mfma16(hi, pf[1][mq], o[mq][ht]);
      }
    }
  }

  // epilogue: reduce l over key-quads, scale, direct store
#pragma unroll
  for (int mq = 0; mq < 2; ++mq) {
    float lv = l_[mq];
    lv += __shfl_xor(lv, 16);
    lv += __shfl_xor(lv, 32);
    const float rl = 1.f / lv;
    const size_t rbase = (size_t)(b * T_ + myq0 + mq * 16 + colL) * (H_ * HD_) + h * HD_;
#pragma unroll
    for (int ht = 0; ht < 8; ++ht) {
      bf16x4 ov;
#pragma unroll
      for (int i = 0; i < 4; ++i) ov[i] = f2bf(o[mq][ht][i] * rl);
      *(bf16x4*)(ao + rbase + ht * 16 + quad * 4) = ov;
    }
  }
}

// ---------------------------------------------------------------------------
extern "C" void kernel_launch(void* const* d_in, const int* in_sizes, int n_in,
                              void* d_out, int out_size, void* d_ws, size_t ws_size,
                              hipStream_t stream) {
  (void)in_sizes; (void)n_in; (void)out_size; (void)ws_size;
  const float* x  = (const float*)d_in[0];
  const float* wq = (const float*)d_in[1];
  const float* bq = (const float*)d_in[2];
  const float* wk = (const float*)d_in[3];
  const float* bk = (const float*)d_in[4];
  const float* wv = (const float*)d_in[5];
  const float* bv = (const float*)d_in[6];
  const float* wo = (const float*)d_in[7];
  float* out = (float*)d_out;

  char* ws = (char*)d_ws;
  bf16* xb    = (bf16*)ws;                 // 16 MiB; reused as ao after QKV gemm
  bf16* wqkvT = (bf16*)(ws + (16u << 20)); // 12 MiB [3072][2048]
  bf16* woT   = (bf16*)(ws + (28u << 20)); //  8 MiB [2048][2048]
  bf16* qkv   = (bf16*)(ws + (36u << 20)); // 24 MiB [4096][3072]
  bf16* kp    = (bf16*)(ws + (60u << 20)); //  8 MiB fragment-major K'
  bf16* vp    = (bf16*)(ws + (68u << 20)); //  8 MiB fragment-major V'

  cast_bf16_kernel<<<dim3(MROWS * C_ / 1024), dim3(256), 0, stream>>>(x, xb, MROWS * C_);

  transpose_cast_qkvw<<<dim3(96, 64), dim3(256), 0, stream>>>(wq, wk, wv, wqkvT);
  transpose_cast<<<dim3(64, 64), dim3(256), 0, stream>>>(wo, woT, 2048, 2048);

  gemm_mfma<true><<<dim3(NQKV / 128, MROWS / 128), dim3(256), 0, stream>>>(
      xb, wqkvT, qkv, bq, bk, bv, MROWS, NQKV, C_);

  rope_bf16<<<dim3(MROWS * 20), dim3(128), 0, stream>>>(qkv);

  pack_k<<<dim3(8 * 64), dim3(256), 0, stream>>>(qkv, kp);
  pack_v<<<dim3(8 * 64), dim3(256), 0, stream>>>(qkv, vp);

  bf16* ao = xb;
  flash_mfma7<<<dim3(2048), dim3(64), 0, stream>>>(qkv, kp, vp, ao);

  gemm_mfma<false><<<dim3(C_ / 128, MROWS / 128), dim3(256), 0, stream>>>(
      ao, woT, out, nullptr, nullptr, nullptr, MROWS, C_, KOFF);
}

// Round 9
// 343.650 us; speedup vs baseline: 1.0773x; 1.0773x over previous
//
#include <hip/hip_runtime.h>
#include <hip/hip_bf16.h>
#include <math.h>

#define B_ 2
#define T_ 2048
#define C_ 2048
#define H_ 16
#define KVH_ 4
#define HD_ 128
#define G_ (H_ / KVH_)
#define MROWS (B_ * T_)                    // 4096
#define NQKV (H_ * HD_ + 2 * KVH_ * HD_)   // 3072
#define KOFF (H_ * HD_)                    // 2048
#define VOFF (H_ * HD_ + KVH_ * HD_)       // 2560

typedef __hip_bfloat16 bf16;
typedef short bf16x8 __attribute__((ext_vector_type(8)));   // 8 bf16 = 4 VGPR
typedef short bf16x4 __attribute__((ext_vector_type(4)));   // 4 bf16 = 2 VGPR
typedef float f32x4 __attribute__((ext_vector_type(4)));

__device__ __forceinline__ void gload_lds16(const void* g, void* l) {
  __builtin_amdgcn_global_load_lds(
      (const __attribute__((address_space(1))) unsigned int*)g,
      (__attribute__((address_space(3))) unsigned int*)l, 16, 0, 0);
}

static __device__ __forceinline__ f32x4 mfma32k(bf16x8 a, bf16x8 b, f32x4 c) {
  return __builtin_amdgcn_mfma_f32_16x16x32_bf16(a, b, c, 0, 0, 0);
}

static __device__ __forceinline__ f32x4 mfma16(bf16x4 a, bf16x4 b, f32x4 c) {
#if __has_builtin(__builtin_amdgcn_mfma_f32_16x16x16_bf16)
  return __builtin_amdgcn_mfma_f32_16x16x16_bf16(a, b, c, 0, 0, 0);
#else
  return __builtin_amdgcn_mfma_f32_16x16x16bf16_1k(a, b, c, 0, 0, 0);
#endif
}

// fast RNE f32->bf16 (no NaN handling; inputs are finite probabilities/sums)
static __device__ __forceinline__ short f2bf(float x) {
  unsigned u = __builtin_bit_cast(unsigned, x);
  u += 0x7FFFu + ((u >> 16) & 1u);
  return (short)(u >> 16);
}

static __device__ __forceinline__ float fexp2(float x) {
#if __has_builtin(__builtin_amdgcn_exp2f)
  return __builtin_amdgcn_exp2f(x);
#else
  return exp2f(x);
#endif
}

// ---------------------------------------------------------------------------
// fp32 -> bf16 elementwise cast
// ---------------------------------------------------------------------------
__global__ void cast_bf16_kernel(const float* __restrict__ in, bf16* __restrict__ out, int n) {
  int i = (blockIdx.x * 256 + threadIdx.x) * 4;
  if (i >= n) return;
  float4 v = *(const float4*)(in + i);
  out[i + 0] = __float2bfloat16(v.x);
  out[i + 1] = __float2bfloat16(v.y);
  out[i + 2] = __float2bfloat16(v.z);
  out[i + 3] = __float2bfloat16(v.w);
}

// ---------------------------------------------------------------------------
// fp32 [R][Ccols] -> bf16 out[Ccols][R]  (for wo)
// ---------------------------------------------------------------------------
__global__ __launch_bounds__(256) void transpose_cast(const float* __restrict__ in,
                                                      bf16* __restrict__ out,
                                                      int R, int Ccols) {
  __shared__ float t[32][33];
  const int tx = threadIdx.x & 31, ty = threadIdx.x >> 5;
  const int r0 = blockIdx.y * 32, c0 = blockIdx.x * 32;
#pragma unroll
  for (int it = 0; it < 4; ++it)
    t[ty + 8 * it][tx] = in[(size_t)(r0 + ty + 8 * it) * Ccols + c0 + tx];
  __syncthreads();
#pragma unroll
  for (int it = 0; it < 4; ++it)
    out[(size_t)(c0 + ty + 8 * it) * R + r0 + tx] = __float2bfloat16(t[tx][ty + 8 * it]);
}

// ---------------------------------------------------------------------------
// Fused wq|wk|wv [2048][*] -> wqkvT [3072][2048] transpose-cast (1 launch)
// ---------------------------------------------------------------------------
__global__ __launch_bounds__(256) void transpose_cast_qkvw(
    const float* __restrict__ wq, const float* __restrict__ wk,
    const float* __restrict__ wv, bf16* __restrict__ outT) {
  __shared__ float t[32][33];
  const int tx = threadIdx.x & 31, ty = threadIdx.x >> 5;
  const int r0 = blockIdx.y * 32;           // k-dim
  const int c0 = blockIdx.x * 32;           // fused n-dim 0..3071
  const float* src;
  int nn, ld;
  if (c0 < KOFF)      { src = wq; nn = c0;        ld = 2048; }
  else if (c0 < VOFF) { src = wk; nn = c0 - KOFF; ld = 512; }
  else                { src = wv; nn = c0 - VOFF; ld = 512; }
#pragma unroll
  for (int it = 0; it < 4; ++it)
    t[ty + 8 * it][tx] = src[(size_t)(r0 + ty + 8 * it) * ld + nn + tx];
  __syncthreads();
#pragma unroll
  for (int it = 0; it < 4; ++it)
    outT[(size_t)(c0 + ty + 8 * it) * 2048 + r0 + tx] = __float2bfloat16(t[tx][ty + 8 * it]);
}

// ---------------------------------------------------------------------------
// RoPE in place on q+k head-rows of qkv (cols 0..2559 = 20 contiguous heads).
// ---------------------------------------------------------------------------
__global__ void rope_bf16(bf16* __restrict__ buf) {
  const int row = blockIdx.x / 20;         // b*T + t
  const int hh = blockIdx.x % 20;          // 0..15 q heads, 16..19 k heads
  const int t = row % T_;
  const int d = threadIdx.x;
  bf16* rp = buf + (size_t)row * NQKV + hh * HD_;
  float vd = __bfloat162float(rp[d]);
  float vp = __bfloat162float(rp[d ^ 64]);
  __syncthreads();
  const int i = d & 63;
  float invf = fexp2(-(float)i * (13.287712379549449f / 64.0f));
  float ang = (float)t * invf;
  float s, c;
  __sincosf(ang, &s, &c);
  rp[d] = __float2bfloat16((d < 64) ? (vd * c - vp * s) : (vd * c + vp * s));
}

// ---------------------------------------------------------------------------
// Pack RoPE'd K into MFMA-fragment-major order (verified r8):
// kp chunk ((bk*64 + tile)*8 + kt*4 + c)*512 + L*8 holds
//   K[b, t = tile*32 + 16*kt + (L&15), kvh][c*32 + (L>>4)*8 .. +8]
// ---------------------------------------------------------------------------
__global__ __launch_bounds__(256) void pack_k(const bf16* __restrict__ qkv,
                                              bf16* __restrict__ kp) {
  const int tile = blockIdx.x & 63;
  const int bk = blockIdx.x >> 6;          // b*KVH + kvh
  const int b = bk >> 2, kvh = bk & 3;
#pragma unroll
  for (int u = 0; u < 2; ++u) {
    const int t = threadIdx.x + u * 256;   // chunk id 0..511
    const int kc = t >> 6, L = t & 63;
    const bf16* src = qkv +
        (size_t)(b * T_ + tile * 32 + 16 * (kc >> 2) + (L & 15)) * NQKV +
        KOFF + kvh * HD_ + (kc & 3) * 32 + (L >> 4) * 8;
    bf16x8 v = *(const bf16x8*)src;
    *(bf16x8*)(kp + ((size_t)(bk * 64 + tile) * 8 + kc) * 512 + L * 8) = v;
  }
}

// ---------------------------------------------------------------------------
// Pack V into PV A-fragment-major order (verified r8):
// vp chunk ((bk*64 + tile)*8 + ht)*512 + L*8 holds 8 bf16:
//   j<4 : V[b, t = tile*32 + (L>>4)*4 + j, kvh][ht*16 + (L&15)]      (kt=0)
//   j>=4: V[b, t = tile*32 + 16 + (L>>4)*4 + (j-4), kvh][ht*16+(L&15)] (kt=1)
// ---------------------------------------------------------------------------
__global__ __launch_bounds__(256) void pack_v(const bf16* __restrict__ qkv,
                                              bf16* __restrict__ vp) {
  const int tile = blockIdx.x & 63;
  const int bk = blockIdx.x >> 6;
  const int b = bk >> 2, kvh = bk & 3;
#pragma unroll
  for (int u = 0; u < 2; ++u) {
    const int t = threadIdx.x + u * 256;
    const int ht = t >> 6, L = t & 63;
    const int colL = L & 15, quad = L >> 4;
    const bf16* base = qkv + (size_t)(b * T_ + tile * 32 + quad * 4) * NQKV +
                       VOFF + kvh * HD_ + ht * 16 + colL;
    bf16x8 v;
#pragma unroll
    for (int j = 0; j < 4; ++j) {
      v[j]     = *(const short*)(base + (size_t)j * NQKV);
      v[j + 4] = *(const short*)(base + (size_t)(16 + j) * NQKV);
    }
    *(bf16x8*)(vp + ((size_t)(bk * 64 + tile) * 8 + ht) * 512 + L * 8) = v;
  }
}

// ---------------------------------------------------------------------------
// bf16 MFMA GEMM (m97 structure): C[M,N] = A[M,K] @ Bt[N,K]^T (+ bias)
// ---------------------------------------------------------------------------
template <bool BF16OUT>
__global__ __launch_bounds__(256, 2) void gemm_mfma(
    const bf16* __restrict__ A, const bf16* __restrict__ Bt, void* __restrict__ Cout,
    const float* __restrict__ bq, const float* __restrict__ bk2,
    const float* __restrict__ bv2, int M, int N, int K) {
  __shared__ __align__(16) bf16 As[128 * 32];
  __shared__ __align__(16) bf16 Bs[128 * 32];
  const int tid = threadIdx.x;
  const int w = tid >> 6, lane = tid & 63;
  const int colL = lane & 15, quad = lane >> 4;
  const int wm = w & 1, wn = w >> 1;
  const int r0 = blockIdx.y * 128, c0 = blockIdx.x * 128;

  f32x4 acc[4][4];
  const f32x4 zero = {0.f, 0.f, 0.f, 0.f};
#pragma unroll
  for (int mt = 0; mt < 4; ++mt)
#pragma unroll
    for (int nt = 0; nt < 4; ++nt) acc[mt][nt] = zero;

  for (int k0 = 0; k0 < K; k0 += 32) {
    __syncthreads();
#pragma unroll
    for (int it = 0; it < 2; ++it) {
      const int seg = it * 4 + w;
      const int idx = seg * 64 + lane;
      const int row = idx >> 2, off = idx & 3;
      gload_lds16(A + (size_t)(r0 + row) * K + k0 + off * 8, &As[seg * 512]);
      gload_lds16(Bt + (size_t)(c0 + row) * K + k0 + off * 8, &Bs[seg * 512]);
    }
    __syncthreads();
    bf16x8 af[4], bfv[4];
#pragma unroll
    for (int mt = 0; mt < 4; ++mt)
      af[mt] = *(const bf16x8*)&As[(wm * 64 + mt * 16 + colL) * 32 + quad * 8];
#pragma unroll
    for (int nt = 0; nt < 4; ++nt)
      bfv[nt] = *(const bf16x8*)&Bs[(wn * 64 + nt * 16 + colL) * 32 + quad * 8];
#pragma unroll
    for (int mt = 0; mt < 4; ++mt)
#pragma unroll
      for (int nt = 0; nt < 4; ++nt)
        acc[mt][nt] =
            __builtin_amdgcn_mfma_f32_16x16x32_bf16(af[mt], bfv[nt], acc[mt][nt], 0, 0, 0);
  }

#pragma unroll
  for (int nt = 0; nt < 4; ++nt) {
    const int c = c0 + wn * 64 + nt * 16 + colL;
    float bias = 0.f;
    if (bq) bias = (c < KOFF) ? bq[c] : (c < VOFF ? bk2[c - KOFF] : bv2[c - VOFF]);
#pragma unroll
    for (int mt = 0; mt < 4; ++mt) {
#pragma unroll
      for (int i = 0; i < 4; ++i) {
        const int r = r0 + wm * 64 + mt * 16 + quad * 4 + i;
        const float v = acc[mt][nt][i] + bias;
        if (BF16OUT)
          ((bf16*)Cout)[(size_t)r * N + c] = __float2bfloat16(v);
        else
          ((float*)Cout)[(size_t)r * N + c] = v;
      }
    }
  }
}

// ---------------------------------------------------------------------------
// Causal GQA flash attention v8: GQA-shared LDS + deep async prefetch +
// cross-tile software pipelining.
// Block = 256 thr = 4 waves = the 4 q-heads of one kv group; all waves share
// the SAME 32 q-rows and kv stream. K/V tiles (fragment-major packed, verified
// r8) staged via global_load_lds into triple buffers (48KB): K prefetched at
// distance 3, V at distance 2; exact-count vmcnt(4/2/0)+s_barrier per tile.
// Pipeline: QK(t+1) is issued BEFORE softmax(t)/PV(t) so the MFMA pipe works
// on the next tile while VALU does the current softmax.
// Work-uniform grid: id -> j = (u<32) ? 63-u : u-32 makes co-resident block
// pairs (id, id+256) sum to 65 tiles. Mask only on final diagonal tile
// (wave-uniform: all waves share q0). Fixed-max softmax (exact, verified r3).
// ---------------------------------------------------------------------------
#define FA_SCL2 (0.08838834764831845f * 1.4426950408889634f)  // scale * log2(e)
#define FA_M2 16.0f                                           // fixed max (exp2 domain)

__global__ __launch_bounds__(256, 2) void flash_mfma8(
    const bf16* __restrict__ qkv, const bf16* __restrict__ kp,
    const bf16* __restrict__ vp, bf16* __restrict__ ao) {
  __shared__ __align__(16) bf16 KS[3][4096];   // 3 x 8KB
  __shared__ __align__(16) bf16 VS[3][4096];   // 3 x 8KB

  const int id = blockIdx.x;
  const int bk = id & 7;                   // b*KVH + kvh
  const int u = id >> 3;                   // 0..63
  const int j = (u < 32) ? (63 - u) : (u - 32);  // pair-sum-constant mapping
  const int b = bk >> 2, kvh = bk & 3;
  const int w = threadIdx.x >> 6;          // wave = q-head within group
  const int h = (kvh << 2) | w;
  const int lane = threadIdx.x & 63;
  const int colL = lane & 15, quad = lane >> 4;
  const int myq0 = j * 32;
  const int nkv = j + 1;

  // per-lane global srcs (wave w stages chunks 2w, 2w+1 of each 8KB tile)
  const bf16* kpt = kp + ((size_t)(bk * 64)) * 4096 + (w * 2) * 512 + lane * 8;
  const bf16* vpt = vp + ((size_t)(bk * 64)) * 4096 + (w * 2) * 512 + lane * 8;

  auto stageK = [&](int tile, int slot) {
    const bf16* s = kpt + (size_t)tile * 4096;
    bf16* d = &KS[slot][(w * 2) * 512];    // wave-uniform base; HW adds lane*16B
    gload_lds16(s, d);
    gload_lds16(s + 512, d + 512);
  };
  auto stageV = [&](int tile, int slot) {
    const bf16* s = vpt + (size_t)tile * 4096;
    bf16* d = &VS[slot][(w * 2) * 512];
    gload_lds16(s, d);
    gload_lds16(s + 512, d + 512);
  };

  // Q fragments (B-operand of K·Q^T): q row = myq0 + mq*16 + colL
  bf16x8 qf[2][4];
  {
    const bf16* qg = qkv + (size_t)(b * T_ + myq0) * NQKV + h * HD_;
#pragma unroll
    for (int mq = 0; mq < 2; ++mq)
#pragma unroll
      for (int c = 0; c < 4; ++c)
        qf[mq][c] = *(const bf16x8*)(qg + (size_t)(mq * 16 + colL) * NQKV + c * 32 + quad * 8);
  }

  const f32x4 zero = {0.f, 0.f, 0.f, 0.f};
  auto qk = [&](const bf16* Kb, f32x4 (&s_)[2][2]) {
    s_[0][0] = zero; s_[0][1] = zero; s_[1][0] = zero; s_[1][1] = zero;
#pragma unroll
    for (int c = 0; c < 4; ++c) {
      bf16x8 kf0 = *(const bf16x8*)(Kb + c * 512 + lane * 8);
      bf16x8 kf1 = *(const bf16x8*)(Kb + (4 + c) * 512 + lane * 8);
#pragma unroll
      for (int mq = 0; mq < 2; ++mq) {
        s_[0][mq] = mfma32k(kf0, qf[mq][c], s_[0][mq]);
        s_[1][mq] = mfma32k(kf1, qf[mq][c], s_[1][mq]);
      }
    }
  };

  f32x4 o[2][8];
#pragma unroll
  for (int mq = 0; mq < 2; ++mq)
#pragma unroll
    for (int ht = 0; ht < 8; ++ht) o[mq][ht] = zero;
  float l_[2] = {0.f, 0.f};

  // prologue: K tiles 0..2, V tiles 0..1; full drain; QK(0)
  stageK(0, 0);
  if (nkv > 1) stageK(1, 1);
  if (nkv > 2) stageK(2, 2);
  stageV(0, 0);
  if (nkv > 1) stageV(1, 1);
  asm volatile("s_waitcnt vmcnt(0)\n\ts_barrier" ::: "memory");

  f32x4 sA[2][2], sB[2][2];
  qk(KS[0], sA);

  int kStage = 0, kNext = 1, vRead = 0, vStage = 2;
#pragma unroll 1
  for (int tt = 0; tt < nkv; ++tt) {
    const bool sk = (tt + 3 < nkv), sv = (tt + 2 < nkv);
    if (sk) stageK(tt + 3, kStage);        // overwrites K(tt) slot: dead since iter tt-1
    if (sv) stageV(tt + 2, vStage);        // overwrites V(tt-1) slot: dead

    // QK(t+1) first: MFMA pipe busy while VALU does softmax(t)
    if (tt + 1 < nkv) qk(KS[kNext], sB);

    // softmax on sA (tile tt); mask only the final diagonal tile
    bf16x4 pf[2][2];
    if (tt == nkv - 1) {
#pragma unroll
      for (int kt = 0; kt < 2; ++kt)
#pragma unroll
        for (int mq = 0; mq < 2; ++mq) {
          const int qc = mq * 16 + colL;
          const int kb = kt * 16 + quad * 4;
          float pv[4];
#pragma unroll
          for (int i = 0; i < 4; ++i) {
            float e = fexp2(fmaf(sA[kt][mq][i], FA_SCL2, -FA_M2));
            pv[i] = (kb + i <= qc) ? e : 0.f;
          }
          l_[mq] += (pv[0] + pv[1]) + (pv[2] + pv[3]);
          pf[kt][mq] = (bf16x4){f2bf(pv[0]), f2bf(pv[1]), f2bf(pv[2]), f2bf(pv[3])};
        }
    } else {
#pragma unroll
      for (int kt = 0; kt < 2; ++kt)
#pragma unroll
        for (int mq = 0; mq < 2; ++mq) {
          float pv[4];
#pragma unroll
          for (int i = 0; i < 4; ++i)
            pv[i] = fexp2(fmaf(sA[kt][mq][i], FA_SCL2, -FA_M2));
          l_[mq] += (pv[0] + pv[1]) + (pv[2] + pv[3]);
          pf[kt][mq] = (bf16x4){f2bf(pv[0]), f2bf(pv[1]), f2bf(pv[2]), f2bf(pv[3])};
        }
    }

    // PV(tt): O^T += V^T · P^T
    {
      const bf16* Vb = VS[vRead];
#pragma unroll
      for (int ht = 0; ht < 8; ++ht) {
        bf16x8 vf8 = *(const bf16x8*)(Vb + ht * 512 + lane * 8);
        bf16x4 lo = __builtin_shufflevector(vf8, vf8, 0, 1, 2, 3);
        bf16x4 hi = __builtin_shufflevector(vf8, vf8, 4, 5, 6, 7);
#pragma unroll
        for (int mq = 0; mq < 2; ++mq) {
          o[mq][ht] = mfma16(lo, pf[0][mq], o[mq][ht]);
          o[mq][ht] = mfma16(hi, pf[1][mq], o[mq][ht]);
        }
      }
    }

    // exact-count wait: only THIS iter's stages may remain outstanding
    if (sk)      asm volatile("s_waitcnt vmcnt(4)\n\ts_barrier" ::: "memory");
    else if (sv) asm volatile("s_waitcnt vmcnt(2)\n\ts_barrier" ::: "memory");
    else         asm volatile("s_waitcnt vmcnt(0)\n\ts_barrier" ::: "memory");

#pragma unroll
    for (int a = 0; a < 2; ++a)
#pragma unroll
      for (int bb = 0; bb < 2; ++bb) sA[a][bb] = sB[a][bb];
    kStage = (kStage == 2) ? 0 : kStage + 1;
    kNext  = (kNext == 2) ? 0 : kNext + 1;
    vRead  = (vRead == 2) ? 0 : vRead + 1;
    vStage = (vStage == 2) ? 0 : vStage + 1;
  }

  // epilogue: reduce l over key-quads, scale, direct store
#pragma unroll
  for (int mq = 0; mq < 2; ++mq) {
    float lv = l_[mq];
    lv += __shfl_xor(lv, 16);
    lv += __shfl_xor(lv, 32);
    const float rl = 1.f / lv;
    const size_t rbase = (size_t)(b * T_ + myq0 + mq * 16 + colL) * (H_ * HD_) + h * HD_;
#pragma unroll
    for (int ht = 0; ht < 8; ++ht) {
      bf16x4 ov;
#pragma unroll
      for (int i = 0; i < 4; ++i) ov[i] = f2bf(o[mq][ht][i] * rl);
      *(bf16x4*)(ao + rbase + ht * 16 + quad * 4) = ov;
    }
  }
}

// ---------------------------------------------------------------------------
extern "C" void kernel_launch(void* const* d_in, const int* in_sizes, int n_in,
                              void* d_out, int out_size, void* d_ws, size_t ws_size,
                              hipStream_t stream) {
  (void)in_sizes; (void)n_in; (void)out_size; (void)ws_size;
  const float* x  = (const float*)d_in[0];
  const float* wq = (const float*)d_in[1];
  const float* bq = (const float*)d_in[2];
  const float* wk = (const float*)d_in[3];
  const float* bk = (const float*)d_in[4];
  const float* wv = (const float*)d_in[5];
  const float* bv = (const float*)d_in[6];
  const float* wo = (const float*)d_in[7];
  float* out = (float*)d_out;

  char* ws = (char*)d_ws;
  bf16* xb    = (bf16*)ws;                 // 16 MiB; reused as ao after QKV gemm
  bf16* wqkvT = (bf16*)(ws + (16u << 20)); // 12 MiB [3072][2048]
  bf16* woT   = (bf16*)(ws + (28u << 20)); //  8 MiB [2048][2048]
  bf16* qkv   = (bf16*)(ws + (36u << 20)); // 24 MiB [4096][3072]
  bf16* kp    = (bf16*)(ws + (60u << 20)); //  8 MiB fragment-major K'
  bf16* vp    = (bf16*)(ws + (68u << 20)); //  8 MiB fragment-major V'

  cast_bf16_kernel<<<dim3(MROWS * C_ / 1024), dim3(256), 0, stream>>>(x, xb, MROWS * C_);

  transpose_cast_qkvw<<<dim3(96, 64), dim3(256), 0, stream>>>(wq, wk, wv, wqkvT);
  transpose_cast<<<dim3(64, 64), dim3(256), 0, stream>>>(wo, woT, 2048, 2048);

  gemm_mfma<true><<<dim3(NQKV / 128, MROWS / 128), dim3(256), 0, stream>>>(
      xb, wqkvT, qkv, bq, bk, bv, MROWS, NQKV, C_);

  rope_bf16<<<dim3(MROWS * 20), dim3(128), 0, stream>>>(qkv);

  pack_k<<<dim3(8 * 64), dim3(256), 0, stream>>>(qkv, kp);
  pack_v<<<dim3(8 * 64), dim3(256), 0, stream>>>(qkv, vp);

  bf16* ao = xb;
  flash_mfma8<<<dim3(512), dim3(256), 0, stream>>>(qkv, kp, vp, ao);

  gemm_mfma<false><<<dim3(C_ / 128, MROWS / 128), dim3(256), 0, stream>>>(
      ao, woT, out, nullptr, nullptr, nullptr, MROWS, C_, KOFF);
}